// Round 4
// baseline (3509.048 us; speedup 1.0000x reference)
//
#include <hip/hip_runtime.h>

#define D   128
#define NN  40000
#define NB  625      // dst buckets per relation (64 nodes each)
#define GH  16       // histogram replica slices
#define GF  256      // fill slices (= fill grid per relation)

struct Ptrs { const int* src[4]; const int* dst[4]; const float* w[4]; };

// ---- K12: full-N LDS histograms for dego (pass0: by src) / degin (pass1: by dst)
// grid = 2 pass x 4 rel x GH reps = 128 blocks; no global atomics (store replicas)
__global__ __launch_bounds__(256) void hist_kernel(
    Ptrs p, float* __restrict__ histo_rep, int E)
{
    __shared__ float hist[NN];          // 156.25 KB
    const int bx = blockIdx.x;
    const int pass = bx & 1;
    const int rel  = (bx >> 1) & 3;
    const int rep  = bx >> 3;           // 0..GH-1
    const int tid = threadIdx.x;

    for (int i = tid; i < NN; i += 256) hist[i] = 0.f;
    __syncthreads();

    const int es  = (E + GH - 1) / GH;
    const int beg = rep * es;
    const int end = min(beg + es, E);
    const int* idx = pass ? p.dst[rel] : p.src[rel];
    const float* w = p.w[rel];
    for (int e = beg + tid; e < end; e += 256)
        atomicAdd(&hist[idx[e]], w[e]);
    __syncthreads();

    float* outp = histo_rep + ((size_t)((pass * 4 + rel) * GH + rep)) * NN;
    for (int i = tid; i < NN; i += 256) outp[i] = hist[i];
}

// ---- reduce replicas -> degio = [dego[4][NN], degin[4][NN]] ----------------
__global__ __launch_bounds__(256) void reduce_kernel(
    const float* __restrict__ histo_rep, float* __restrict__ degio, int total)
{
    int i = blockIdx.x * 256 + threadIdx.x;     // i = pr*NN + node
    if (i >= total) return;
    int pr = i / NN;
    int node = i - pr * NN;
    float v = 0.f;
#pragma unroll
    for (int r = 0; r < GH; ++r) v += histo_rep[((size_t)(pr * GH + r)) * NN + node];
    degio[i] = v;
}

// ---- K_bcnt: per-(rel,slice) bucket counts in tiny LDS ---------------------
// grid = 4 rel x GF slices = 1024 blocks
__global__ __launch_bounds__(256) void bcnt_kernel(
    Ptrs p, int* __restrict__ cnt_store, int E)
{
    __shared__ int cnt[NB];
    const int rel = blockIdx.x >> 8;
    const int rep = blockIdx.x & (GF - 1);
    const int tid = threadIdx.x;
    for (int b = tid; b < NB; b += 256) cnt[b] = 0;
    __syncthreads();
    const int es  = (E + GF - 1) / GF;
    const int beg = rep * es;
    const int end = min(beg + es, E);
    const int* dst = p.dst[rel];
    for (int e = beg + tid; e < end; e += 256)
        atomicAdd(&cnt[dst[e] >> 6], 1);
    __syncthreads();
    for (int b = tid; b < NB; b += 256)
        cnt_store[((size_t)(rel * NB + b)) * GF + rep] = cnt[b];
}

// ---- 3-kernel scan over 4*NB*GF = 640000 counts ----------------------------
__device__ inline int block_excl_scan(int v, int tid) {
    __shared__ int wsum[16];
    int lane = tid & 63, wid = tid >> 6;
    int x = v;
#pragma unroll
    for (int off = 1; off < 64; off <<= 1) {
        int y = __shfl_up(x, off, 64);
        if (lane >= off) x += y;
    }
    if (lane == 63) wsum[wid] = x;
    __syncthreads();
    if (wid == 0) {
        int y = (lane < 16) ? wsum[lane] : 0;
#pragma unroll
        for (int off = 1; off < 16; off <<= 1) {
            int t = __shfl_up(y, off, 64);
            if (lane >= off) y += t;
        }
        if (lane < 16) wsum[lane] = y;
    }
    __syncthreads();
    int woff = wid ? wsum[wid - 1] : 0;
    return woff + x - v;
}

__global__ __launch_bounds__(1024) void scan1_kernel(
    const int* __restrict__ cnt_store, int* __restrict__ scanex,
    int* __restrict__ bsum, int total)
{
    int tid = threadIdx.x;
    int i = blockIdx.x * 1024 + tid;
    int v = (i < total) ? cnt_store[i] : 0;
    int excl = block_excl_scan(v, tid);
    if (i < total) scanex[i] = excl;
    if (tid == 1023) bsum[blockIdx.x] = excl + v;
}

__global__ __launch_bounds__(1024) void scan2_kernel(int* __restrict__ bsum, int nb)
{
    int tid = threadIdx.x;
    int v = (tid < nb) ? bsum[tid] : 0;
    int excl = block_excl_scan(v, tid);
    if (tid < nb) bsum[tid] = excl;
}

__global__ __launch_bounds__(256) void scan3_kernel(
    const int* __restrict__ scanex, const int* __restrict__ bsum,
    int* __restrict__ cursor_base, int* __restrict__ bucket_ptr,
    int total, int E)
{
    int i = blockIdx.x * 256 + threadIdx.x;
    if (i >= total) return;
    int v = scanex[i] + bsum[i >> 10];
    int rel = i / (NB * GF);
    int rem = i - rel * (NB * GF);
    int b = rem >> 8, rep = rem & (GF - 1);
    int local = v - rel * E;            // each relation has exactly E edges
    cursor_base[i] = local;
    if (rep == 0) bucket_ptr[rel * (NB + 1) + b] = local;
    if (rem == 0) bucket_ptr[rel * (NB + 1) + NB] = E;
}

// ---- fill: bucket-sort records; LDS cursors only (no global atomics) -------
// grid = GF blocks (one relation per launch)
__global__ __launch_bounds__(256) void fill_kernel(
    const int* __restrict__ src, const int* __restrict__ dst,
    const float* __restrict__ w, const float* __restrict__ dego,
    const float* __restrict__ degin, const int* __restrict__ cursor_base_r,
    unsigned long long* __restrict__ csr8, int E)
{
    __shared__ int lcur[NB];
    const int rep = blockIdx.x;
    const int tid = threadIdx.x;
    for (int b = tid; b < NB; b += 256)
        lcur[b] = cursor_base_r[(size_t)b * GF + rep];
    __syncthreads();
    const int es  = (E + GF - 1) / GF;
    const int beg = rep * es;
    const int end = min(beg + es, E);
    for (int e = beg + tid; e < end; e += 256) {
        int s = src[e];
        int d = dst[e];
        float wn = w[e] * rsqrtf(dego[s] * degin[d]);
        int pos = atomicAdd(&lcur[d >> 6], 1);
        unsigned long long rec =
            (unsigned long long)(unsigned)(s | ((d & 63) << 16)) |
            ((unsigned long long)__float_as_uint(wn) << 32);
        csr8[pos] = rec;
    }
}

// ---- accumulate: one block per bucket; 64x128 LDS tile; ds_add_f32 ---------
__global__ __launch_bounds__(256) void accum_kernel(
    const int* __restrict__ bucket_ptr_r, const unsigned long long* __restrict__ csr8,
    const float* __restrict__ h, float* __restrict__ agg)
{
    __shared__ float tile[64 * D];      // 32 KB
    const int b = blockIdx.x;
    const int tid = threadIdx.x;
    const int wid = tid >> 6;
    const int lane = tid & 63;
    for (int i = tid; i < 64 * D; i += 256) tile[i] = 0.f;
    __syncthreads();
    const int beg = bucket_ptr_r[b];
    const int end = bucket_ptr_r[b + 1];
    for (int e = beg + wid; e < end; e += 4) {
        unsigned long long rec = csr8[e];      // uniform across wave: broadcast
        int s = (int)(rec & 0xFFFF);
        int j = (int)((rec >> 16) & 63);
        float wn = __uint_as_float((unsigned)(rec >> 32));
        const float* hr = h + (size_t)s * D;
        float v0 = hr[lane];
        float v1 = hr[lane + 64];
        atomicAdd(&tile[j * D + lane], wn * v0);        // bank = lane&31: 2-way, free
        atomicAdd(&tile[j * D + 64 + lane], wn * v1);
    }
    __syncthreads();
    float* ab = agg + (size_t)b * 64 * D;
    for (int i = tid; i < 64 * D; i += 256) ab[i] = tile[i];
}

// ---- proj: agg @ W, fused bias+ReLU+0.5*merge ------------------------------
__global__ __launch_bounds__(256) void proj_fused_kernel(
    const float* __restrict__ h, const float* __restrict__ W,
    const float* __restrict__ b, float* __restrict__ out, int add)
{
    __shared__ float Ws[64 * D];
    __shared__ float Hs[32 * D];
    const int t = threadIdx.x;
    const int row0 = blockIdx.x * 32;

    const float4* H4 = (const float4*)(h + (size_t)row0 * D);
    float4* Hs4 = (float4*)Hs;
#pragma unroll
    for (int i = 0; i < 4; ++i) Hs4[t + 256 * i] = H4[t + 256 * i];

    const int c0 = (t & 31) * 4;
    const int r0 = (t >> 5) * 4;
    float acc[4][4] = {};

    for (int kc = 0; kc < 2; ++kc) {
        __syncthreads();
        const float4* W4 = (const float4*)(W + (size_t)kc * 64 * D);
        float4* Ws4 = (float4*)Ws;
#pragma unroll
        for (int i = 0; i < 8; ++i) Ws4[t + 256 * i] = W4[t + 256 * i];
        __syncthreads();

        for (int k = 0; k < 64; ++k) {
            float4 wv = *(const float4*)&Ws[k * D + c0];
            float h0 = Hs[(r0 + 0) * D + kc * 64 + k];
            float h1 = Hs[(r0 + 1) * D + kc * 64 + k];
            float h2 = Hs[(r0 + 2) * D + kc * 64 + k];
            float h3 = Hs[(r0 + 3) * D + kc * 64 + k];
            acc[0][0] += h0 * wv.x; acc[0][1] += h0 * wv.y; acc[0][2] += h0 * wv.z; acc[0][3] += h0 * wv.w;
            acc[1][0] += h1 * wv.x; acc[1][1] += h1 * wv.y; acc[1][2] += h1 * wv.z; acc[1][3] += h1 * wv.w;
            acc[2][0] += h2 * wv.x; acc[2][1] += h2 * wv.y; acc[2][2] += h2 * wv.z; acc[2][3] += h2 * wv.w;
            acc[3][0] += h3 * wv.x; acc[3][1] += h3 * wv.y; acc[3][2] += h3 * wv.z; acc[3][3] += h3 * wv.w;
        }
    }

    float4 bv = *(const float4*)&b[c0];
#pragma unroll
    for (int r = 0; r < 4; ++r) {
        float* op = &out[(size_t)(row0 + r0 + r) * D + c0];
        float4 v;
        v.x = 0.5f * fmaxf(acc[r][0] + bv.x, 0.0f);
        v.y = 0.5f * fmaxf(acc[r][1] + bv.y, 0.0f);
        v.z = 0.5f * fmaxf(acc[r][2] + bv.z, 0.0f);
        v.w = 0.5f * fmaxf(acc[r][3] + bv.w, 0.0f);
        if (add) {
            float4 o = *(const float4*)op;
            v.x += o.x; v.y += o.y; v.z += o.z; v.w += o.w;
        }
        *(float4*)op = v;
    }
}

extern "C" void kernel_launch(void* const* d_in, const int* in_sizes, int n_in,
                              void* d_out, int out_size, void* d_ws, size_t ws_size,
                              hipStream_t stream) {
    const float* com_emb = (const float*)d_in[0];
    const float* pos_emb = (const float*)d_in[1];
    const int E = in_sizes[2];       // 1,000,000
    const int N = NN;

    float* out = (float*)d_out;
    float* out_com = out;
    float* out_pos = out + (size_t)N * D;

    // relation order: 0=cflow(com->com) 1=supply(pos->com) 2=pflow(pos->pos) 3=demand(com->pos)
    Ptrs ptrs;
    ptrs.src[0] = (const int*)d_in[8];  ptrs.dst[0] = (const int*)d_in[9];  ptrs.w[0] = (const float*)d_in[10];
    ptrs.src[1] = (const int*)d_in[5];  ptrs.dst[1] = (const int*)d_in[6];  ptrs.w[1] = (const float*)d_in[7];
    ptrs.src[2] = (const int*)d_in[11]; ptrs.dst[2] = (const int*)d_in[12]; ptrs.w[2] = (const float*)d_in[13];
    ptrs.src[3] = (const int*)d_in[2];  ptrs.dst[3] = (const int*)d_in[3];  ptrs.w[3] = (const float*)d_in[4];

    // ws layout (~38 MB): histo_rep overlaid with agg (histo_rep dead after reduce)
    const int totalCnt = 4 * NB * GF;           // 640000
    char* p = (char*)d_ws;
    float* degio       = (float*)p;  p += (size_t)8 * N * 4;              // 1.28 MB
    int*   cnt_store   = (int*)p;    p += (size_t)totalCnt * 4;           // 2.56 MB
    int*   scanex      = (int*)p;    p += (size_t)totalCnt * 4;           // 2.56 MB
    int*   bsum        = (int*)p;    p += (size_t)1024 * 4;
    int*   cursor_base = (int*)p;    p += (size_t)totalCnt * 4;           // 2.56 MB
    int*   bucket_ptr  = (int*)p;    p += (size_t)4 * (NB + 1) * 4;
    unsigned long long* csr8 = (unsigned long long*)p; p += (size_t)E * 8; // 8 MB
    float* histo_rep   = (float*)p;                                       // 20.48 MB
    float* agg         = (float*)p;                                       // (overlay)

    float* dego  = degio;
    float* degin = degio + (size_t)4 * N;

    hist_kernel<<<2 * 4 * GH, 256, 0, stream>>>(ptrs, histo_rep, E);
    reduce_kernel<<<(8 * N + 255) / 256, 256, 0, stream>>>(histo_rep, degio, 8 * N);
    bcnt_kernel<<<4 * GF, 256, 0, stream>>>(ptrs, cnt_store, E);
    scan1_kernel<<<(totalCnt + 1023) / 1024, 1024, 0, stream>>>(cnt_store, scanex, bsum, totalCnt);
    scan2_kernel<<<1, 1024, 0, stream>>>(bsum, (totalCnt + 1023) / 1024);
    scan3_kernel<<<(totalCnt + 255) / 256, 256, 0, stream>>>(scanex, bsum, cursor_base,
                                                             bucket_ptr, totalCnt, E);

    const int pBlocks = N / 32;
    auto run_rel = [&](int rel, const float* h, const float* W, const float* b,
                       float* oh, int add) {
        fill_kernel<<<GF, 256, 0, stream>>>(ptrs.src[rel], ptrs.dst[rel], ptrs.w[rel],
                                            dego + (size_t)rel * N, degin + (size_t)rel * N,
                                            cursor_base + (size_t)rel * NB * GF, csr8, E);
        accum_kernel<<<NB, 256, 0, stream>>>(bucket_ptr + (size_t)rel * (NB + 1), csr8, h, agg);
        proj_fused_kernel<<<pBlocks, 256, 0, stream>>>(agg, W, b, oh, add);
    };

    run_rel(0, com_emb, (const float*)d_in[18], (const float*)d_in[19], out_com, 0); // cflow
    run_rel(1, pos_emb, (const float*)d_in[16], (const float*)d_in[17], out_com, 1); // supply
    run_rel(2, pos_emb, (const float*)d_in[20], (const float*)d_in[21], out_pos, 0); // pflow
    run_rel(3, com_emb, (const float*)d_in[14], (const float*)d_in[15], out_pos, 1); // demand
}

// Round 5
// 764.740 us; speedup vs baseline: 4.5885x; 4.5885x over previous
//
#include <hip/hip_runtime.h>

#define D   128
#define NN  40000
#define NB  625      // dst buckets per relation (64 nodes each)
#define GH  16       // histogram replica slices
#define GF  128      // fill slices (= fill grid per relation)

struct Ptrs { const int* src[4]; const int* dst[4]; const float* w[4]; };

// ---- full-N LDS histograms: dego (pass0: by src) / degin (pass1: by dst) ---
// grid = 2 pass x 4 rel x GH reps = 128 blocks; no global atomics
__global__ __launch_bounds__(256) void hist_kernel(
    Ptrs p, float* __restrict__ histo_rep, int E)
{
    __shared__ float hist[NN];          // 156.25 KB
    const int bx = blockIdx.x;
    const int pass = bx & 1;
    const int rel  = (bx >> 1) & 3;
    const int rep  = bx >> 3;
    const int tid = threadIdx.x;

    for (int i = tid; i < NN; i += 256) hist[i] = 0.f;
    __syncthreads();

    const int es  = (E + GH - 1) / GH;
    const int beg = rep * es;
    const int end = min(beg + es, E);
    const int* idx = pass ? p.dst[rel] : p.src[rel];
    const float* w = p.w[rel];
    for (int e = beg + tid; e < end; e += 256)
        atomicAdd(&hist[idx[e]], w[e]);
    __syncthreads();

    float* outp = histo_rep + ((size_t)((pass * 4 + rel) * GH + rep)) * NN;
    for (int i = tid; i < NN; i += 256) outp[i] = hist[i];
}

__global__ __launch_bounds__(256) void reduce_kernel(
    const float* __restrict__ histo_rep, float* __restrict__ degio, int total)
{
    int i = blockIdx.x * 256 + threadIdx.x;     // i = pr*NN + node
    if (i >= total) return;
    int pr = i / NN;
    int node = i - pr * NN;
    float v = 0.f;
#pragma unroll
    for (int r = 0; r < GH; ++r) v += histo_rep[((size_t)(pr * GH + r)) * NN + node];
    degio[i] = v;
}

// ---- per-(rel,slice) coarse bucket counts in tiny LDS ----------------------
__global__ __launch_bounds__(256) void bcnt_kernel(
    Ptrs p, int* __restrict__ cnt_store, int E)
{
    __shared__ int cnt[NB];
    const int rel = blockIdx.x / GF;
    const int rep = blockIdx.x - rel * GF;
    const int tid = threadIdx.x;
    for (int b = tid; b < NB; b += 256) cnt[b] = 0;
    __syncthreads();
    const int es  = (E + GF - 1) / GF;
    const int beg = rep * es;
    const int end = min(beg + es, E);
    const int* dst = p.dst[rel];
    for (int e = beg + tid; e < end; e += 256)
        atomicAdd(&cnt[dst[e] >> 6], 1);
    __syncthreads();
    for (int b = tid; b < NB; b += 256)
        cnt_store[((size_t)(rel * NB + b)) * GF + rep] = cnt[b];
}

// ---- 3-kernel scan over 4*NB*GF = 320000 counts ----------------------------
__device__ inline int block_excl_scan(int v, int tid) {
    __shared__ int wsum[16];
    int lane = tid & 63, wid = tid >> 6;
    int x = v;
#pragma unroll
    for (int off = 1; off < 64; off <<= 1) {
        int y = __shfl_up(x, off, 64);
        if (lane >= off) x += y;
    }
    if (lane == 63) wsum[wid] = x;
    __syncthreads();
    if (wid == 0) {
        int y = (lane < 16) ? wsum[lane] : 0;
#pragma unroll
        for (int off = 1; off < 16; off <<= 1) {
            int t = __shfl_up(y, off, 64);
            if (lane >= off) y += t;
        }
        if (lane < 16) wsum[lane] = y;
    }
    __syncthreads();
    int woff = wid ? wsum[wid - 1] : 0;
    return woff + x - v;
}

__global__ __launch_bounds__(1024) void scan1_kernel(
    const int* __restrict__ cnt_store, int* __restrict__ scanex,
    int* __restrict__ bsum, int total)
{
    int tid = threadIdx.x;
    int i = blockIdx.x * 1024 + tid;
    int v = (i < total) ? cnt_store[i] : 0;
    int excl = block_excl_scan(v, tid);
    if (i < total) scanex[i] = excl;
    if (tid == 1023) bsum[blockIdx.x] = excl + v;
}

__global__ __launch_bounds__(1024) void scan2_kernel(int* __restrict__ bsum, int nb)
{
    int tid = threadIdx.x;
    int v = (tid < nb) ? bsum[tid] : 0;
    int excl = block_excl_scan(v, tid);
    if (tid < nb) bsum[tid] = excl;
}

__global__ __launch_bounds__(256) void scan3_kernel(
    const int* __restrict__ scanex, const int* __restrict__ bsum,
    int* __restrict__ cursor_base, int* __restrict__ bucket_ptr,
    int total, int E)
{
    int i = blockIdx.x * 256 + threadIdx.x;
    if (i >= total) return;
    int v = scanex[i] + bsum[i >> 10];
    int rel = i / (NB * GF);
    int rem = i - rel * (NB * GF);
    int b = rem / GF, rep = rem - b * GF;
    int local = v - rel * E;            // each relation has exactly E edges
    cursor_base[i] = local;
    if (rep == 0) bucket_ptr[rel * (NB + 1) + b] = local;
    if (rem == 0) bucket_ptr[rel * (NB + 1) + NB] = E;
}

// ---- fill: coarse bucket sort; LDS cursors; wn fully baked -----------------
__global__ __launch_bounds__(256) void fill_kernel(
    const int* __restrict__ src, const int* __restrict__ dst,
    const float* __restrict__ w, const float* __restrict__ dego,
    const float* __restrict__ degin, const int* __restrict__ cursor_base_r,
    unsigned long long* __restrict__ csr8, int E)
{
    __shared__ int lcur[NB];
    const int rep = blockIdx.x;
    const int tid = threadIdx.x;
    for (int b = tid; b < NB; b += 256)
        lcur[b] = cursor_base_r[(size_t)b * GF + rep];
    __syncthreads();
    const int es  = (E + GF - 1) / GF;
    const int beg = rep * es;
    const int end = min(beg + es, E);
    for (int e = beg + tid; e < end; e += 256) {
        int s = src[e];
        int d = dst[e];
        float wn = w[e] * rsqrtf(dego[s] * degin[d]);
        int pos = atomicAdd(&lcur[d >> 6], 1);
        unsigned long long rec =
            (unsigned long long)(unsigned)(s | ((d & 63) << 16)) |
            ((unsigned long long)__float_as_uint(wn) << 32);
        csr8[pos] = rec;
    }
}

// ---- sort2: bucket -> exact per-dst CSR (64 LDS bins) + row_ptr ------------
__global__ __launch_bounds__(256) void sort2_kernel(
    const int* __restrict__ bucket_ptr_r, const unsigned long long* __restrict__ csr8,
    unsigned long long* __restrict__ csr2, int* __restrict__ row_ptr_r, int E)
{
    __shared__ int cnt[64];
    __shared__ int cur[64];
    const int b = blockIdx.x;
    const int tid = threadIdx.x;
    const int beg = bucket_ptr_r[b];
    const int end = bucket_ptr_r[b + 1];
    if (tid < 64) cnt[tid] = 0;
    __syncthreads();
    for (int e = beg + tid; e < end; e += 256)
        atomicAdd(&cnt[(int)((csr8[e] >> 16) & 63)], 1);
    __syncthreads();
    if (tid < 64) {                      // wave 0: exclusive scan of 64 bins
        int v = cnt[tid];
        int x = v;
#pragma unroll
        for (int off = 1; off < 64; off <<= 1) {
            int y = __shfl_up(x, off, 64);
            if (tid >= off) x += y;
        }
        int start = beg + x - v;
        cur[tid] = start;
        row_ptr_r[b * 64 + tid] = start;
        if (b == 0 && tid == 0) row_ptr_r[NN] = E;
    }
    __syncthreads();
    for (int e = beg + tid; e < end; e += 256) {
        unsigned long long rec = csr8[e];
        int j = (int)((rec >> 16) & 63);
        int pos = atomicAdd(&cur[j], 1);
        csr2[pos] = rec;
    }
}

// ---- gather: one wave per dst node over exact CSR --------------------------
__global__ __launch_bounds__(256) void gather_kernel(
    const int* __restrict__ row_ptr_r, const unsigned long long* __restrict__ csr2,
    const float* __restrict__ h, float* __restrict__ agg, int n)
{
    int node = (blockIdx.x * 256 + threadIdx.x) >> 6;
    int lane = threadIdx.x & 63;
    if (node >= n) return;
    int beg = row_ptr_r[node], end = row_ptr_r[node + 1];
    float2 acc = make_float2(0.f, 0.f);
    for (int e = beg; e < end; ++e) {
        unsigned long long rec = csr2[e];          // uniform: broadcast
        int s = (int)(rec & 0xFFFF);
        float wn = __uint_as_float((unsigned)(rec >> 32));
        float2 hv = *(const float2*)(h + (size_t)s * D + lane * 2);
        acc.x += wn * hv.x;
        acc.y += wn * hv.y;
    }
    *(float2*)(agg + (size_t)node * D + lane * 2) = acc;
}

// ---- proj: agg @ W, fused bias+ReLU+0.5*merge ------------------------------
__global__ __launch_bounds__(256) void proj_fused_kernel(
    const float* __restrict__ h, const float* __restrict__ W,
    const float* __restrict__ b, float* __restrict__ out, int add)
{
    __shared__ float Ws[64 * D];
    __shared__ float Hs[32 * D];
    const int t = threadIdx.x;
    const int row0 = blockIdx.x * 32;

    const float4* H4 = (const float4*)(h + (size_t)row0 * D);
    float4* Hs4 = (float4*)Hs;
#pragma unroll
    for (int i = 0; i < 4; ++i) Hs4[t + 256 * i] = H4[t + 256 * i];

    const int c0 = (t & 31) * 4;
    const int r0 = (t >> 5) * 4;
    float acc[4][4] = {};

    for (int kc = 0; kc < 2; ++kc) {
        __syncthreads();
        const float4* W4 = (const float4*)(W + (size_t)kc * 64 * D);
        float4* Ws4 = (float4*)Ws;
#pragma unroll
        for (int i = 0; i < 8; ++i) Ws4[t + 256 * i] = W4[t + 256 * i];
        __syncthreads();

        for (int k = 0; k < 64; ++k) {
            float4 wv = *(const float4*)&Ws[k * D + c0];
            float h0 = Hs[(r0 + 0) * D + kc * 64 + k];
            float h1 = Hs[(r0 + 1) * D + kc * 64 + k];
            float h2 = Hs[(r0 + 2) * D + kc * 64 + k];
            float h3 = Hs[(r0 + 3) * D + kc * 64 + k];
            acc[0][0] += h0 * wv.x; acc[0][1] += h0 * wv.y; acc[0][2] += h0 * wv.z; acc[0][3] += h0 * wv.w;
            acc[1][0] += h1 * wv.x; acc[1][1] += h1 * wv.y; acc[1][2] += h1 * wv.z; acc[1][3] += h1 * wv.w;
            acc[2][0] += h2 * wv.x; acc[2][1] += h2 * wv.y; acc[2][2] += h2 * wv.z; acc[2][3] += h2 * wv.w;
            acc[3][0] += h3 * wv.x; acc[3][1] += h3 * wv.y; acc[3][2] += h3 * wv.z; acc[3][3] += h3 * wv.w;
        }
    }

    float4 bv = *(const float4*)&b[c0];
#pragma unroll
    for (int r = 0; r < 4; ++r) {
        float* op = &out[(size_t)(row0 + r0 + r) * D + c0];
        float4 v;
        v.x = 0.5f * fmaxf(acc[r][0] + bv.x, 0.0f);
        v.y = 0.5f * fmaxf(acc[r][1] + bv.y, 0.0f);
        v.z = 0.5f * fmaxf(acc[r][2] + bv.z, 0.0f);
        v.w = 0.5f * fmaxf(acc[r][3] + bv.w, 0.0f);
        if (add) {
            float4 o = *(const float4*)op;
            v.x += o.x; v.y += o.y; v.z += o.z; v.w += o.w;
        }
        *(float4*)op = v;
    }
}

extern "C" void kernel_launch(void* const* d_in, const int* in_sizes, int n_in,
                              void* d_out, int out_size, void* d_ws, size_t ws_size,
                              hipStream_t stream) {
    const float* com_emb = (const float*)d_in[0];
    const float* pos_emb = (const float*)d_in[1];
    const int E = in_sizes[2];       // 1,000,000
    const int N = NN;

    float* out = (float*)d_out;
    float* out_com = out;
    float* out_pos = out + (size_t)N * D;

    // relation order: 0=cflow(com->com) 1=supply(pos->com) 2=pflow(pos->pos) 3=demand(com->pos)
    Ptrs ptrs;
    ptrs.src[0] = (const int*)d_in[8];  ptrs.dst[0] = (const int*)d_in[9];  ptrs.w[0] = (const float*)d_in[10];
    ptrs.src[1] = (const int*)d_in[5];  ptrs.dst[1] = (const int*)d_in[6];  ptrs.w[1] = (const float*)d_in[7];
    ptrs.src[2] = (const int*)d_in[11]; ptrs.dst[2] = (const int*)d_in[12]; ptrs.w[2] = (const float*)d_in[13];
    ptrs.src[3] = (const int*)d_in[2];  ptrs.dst[3] = (const int*)d_in[3];  ptrs.w[3] = (const float*)d_in[4];

    // ws layout (~42.2 MB); histo_rep overlaid with agg (dead after reduce)
    const int totalCnt = 4 * NB * GF;           // 320000
    char* p = (char*)d_ws;
    float* degio       = (float*)p;  p += (size_t)8 * N * 4;              // 1.28 MB
    int*   cnt_store   = (int*)p;    p += (size_t)totalCnt * 4;           // 1.28 MB
    int*   scanex      = (int*)p;    p += (size_t)totalCnt * 4;           // 1.28 MB
    int*   bsum        = (int*)p;    p += (size_t)1024 * 4;
    int*   cursor_base = (int*)p;    p += (size_t)totalCnt * 4;           // 1.28 MB
    int*   bucket_ptr  = (int*)p;    p += (size_t)4 * (NB + 1) * 4;
    int*   row_ptr     = (int*)p;    p += (size_t)4 * (N + 1) * 4;        // 0.64 MB
    unsigned long long* csr8 = (unsigned long long*)p; p += (size_t)E * 8; // 8 MB
    unsigned long long* csr2 = (unsigned long long*)p; p += (size_t)E * 8; // 8 MB
    float* histo_rep   = (float*)p;                                       // 20.48 MB
    float* agg         = (float*)p;                                       // (overlay)

    float* dego  = degio;
    float* degin = degio + (size_t)4 * N;

    hist_kernel<<<2 * 4 * GH, 256, 0, stream>>>(ptrs, histo_rep, E);
    reduce_kernel<<<(8 * N + 255) / 256, 256, 0, stream>>>(histo_rep, degio, 8 * N);
    bcnt_kernel<<<4 * GF, 256, 0, stream>>>(ptrs, cnt_store, E);
    scan1_kernel<<<(totalCnt + 1023) / 1024, 1024, 0, stream>>>(cnt_store, scanex, bsum, totalCnt);
    scan2_kernel<<<1, 1024, 0, stream>>>(bsum, (totalCnt + 1023) / 1024);
    scan3_kernel<<<(totalCnt + 255) / 256, 256, 0, stream>>>(scanex, bsum, cursor_base,
                                                             bucket_ptr, totalCnt, E);

    const int gBlocks = N / 4;                 // 1 wave per dst node
    const int pBlocks = N / 32;
    auto run_rel = [&](int rel, const float* h, const float* W, const float* b,
                       float* oh, int add) {
        int* rp = row_ptr + (size_t)rel * (N + 1);
        fill_kernel<<<GF, 256, 0, stream>>>(ptrs.src[rel], ptrs.dst[rel], ptrs.w[rel],
                                            dego + (size_t)rel * N, degin + (size_t)rel * N,
                                            cursor_base + (size_t)rel * NB * GF, csr8, E);
        sort2_kernel<<<NB, 256, 0, stream>>>(bucket_ptr + (size_t)rel * (NB + 1), csr8,
                                             csr2, rp, E);
        gather_kernel<<<gBlocks, 256, 0, stream>>>(rp, csr2, h, agg, N);
        proj_fused_kernel<<<pBlocks, 256, 0, stream>>>(agg, W, b, oh, add);
    };

    run_rel(0, com_emb, (const float*)d_in[18], (const float*)d_in[19], out_com, 0); // cflow
    run_rel(1, pos_emb, (const float*)d_in[16], (const float*)d_in[17], out_com, 1); // supply
    run_rel(2, pos_emb, (const float*)d_in[20], (const float*)d_in[21], out_pos, 0); // pflow
    run_rel(3, com_emb, (const float*)d_in[14], (const float*)d_in[15], out_pos, 1); // demand
}

// Round 6
// 538.298 us; speedup vs baseline: 6.5188x; 1.4207x over previous
//
#include <hip/hip_runtime.h>

#define D   128
#define NN  40000
#define HH  20000    // histogram half-table size (78.125 KB LDS)
#define NB  625      // dst buckets per relation (64 nodes each)
#define GH  32       // histogram replica slices
#define GF  128      // fill slices (= fill grid per relation)

typedef unsigned long long ull;

struct Ptrs { const int* src[4]; const int* dst[4]; const float* w[4]; };

// ---- weighted out-degree: half-table LDS histograms, 2 blocks/CU -----------
// grid = 4 rel x 2 half x GH reps = 256 blocks x 1024 threads; no global atomics
__global__ __launch_bounds__(1024) void hist_kernel(
    Ptrs p, float* __restrict__ histo_rep, int E)
{
    __shared__ float hist[HH];          // 78.125 KB -> 2 blocks/CU, 32 waves
    const int bx   = blockIdx.x;        // ((rel*2 + half)*GH + rep)
    const int rep  = bx & (GH - 1);
    const int half = (bx >> 5) & 1;
    const int rel  = bx >> 6;
    const int tid  = threadIdx.x;

    for (int i = tid; i < HH; i += 1024) hist[i] = 0.f;
    __syncthreads();

    const int es  = (E + GH - 1) / GH;
    const int beg = rep * es;
    const int end = min(beg + es, E);
    const int* idx = p.src[rel];
    const float* w = p.w[rel];
    const int base = half * HH;
    for (int e = beg + tid; e < end; e += 1024) {
        int v = idx[e] - base;
        if ((unsigned)v < HH) atomicAdd(&hist[v], w[e]);
    }
    __syncthreads();

    float* outp = histo_rep + (size_t)bx * HH;
    for (int i = tid; i < HH; i += 1024) outp[i] = hist[i];
}

// ---- reduce replicas -> rdego[rel][node] = rsqrt(weighted out-degree) ------
__global__ __launch_bounds__(256) void reduce_kernel(
    const float* __restrict__ histo_rep, float* __restrict__ rdego, int total)
{
    int i = blockIdx.x * 256 + threadIdx.x;     // i = rel*NN + node
    if (i >= total) return;
    int rel = i / NN;
    int node = i - rel * NN;
    int half = node / HH;
    int hn = node - half * HH;
    const float* basep = histo_rep + ((size_t)((rel * 2 + half) * GH)) * HH + hn;
    float v = 0.f;
#pragma unroll
    for (int r = 0; r < GH; ++r) v += basep[(size_t)r * HH];
    rdego[i] = rsqrtf(v);
}

// ---- per-(rel,slice) coarse bucket counts in tiny LDS ----------------------
__global__ __launch_bounds__(256) void bcnt_kernel(
    Ptrs p, int* __restrict__ cnt_store, int E)
{
    __shared__ int cnt[NB];
    const int rel = blockIdx.x / GF;
    const int rep = blockIdx.x - rel * GF;
    const int tid = threadIdx.x;
    for (int b = tid; b < NB; b += 256) cnt[b] = 0;
    __syncthreads();
    const int es  = (E + GF - 1) / GF;
    const int beg = rep * es;
    const int end = min(beg + es, E);
    const int* dst = p.dst[rel];
    for (int e = beg + tid; e < end; e += 256)
        atomicAdd(&cnt[dst[e] >> 6], 1);
    __syncthreads();
    for (int b = tid; b < NB; b += 256)
        cnt_store[((size_t)(rel * NB + b)) * GF + rep] = cnt[b];
}

// ---- 3-kernel scan over 4*NB*GF = 320000 counts ----------------------------
__device__ inline int block_excl_scan(int v, int tid) {
    __shared__ int wsum[16];
    int lane = tid & 63, wid = tid >> 6;
    int x = v;
#pragma unroll
    for (int off = 1; off < 64; off <<= 1) {
        int y = __shfl_up(x, off, 64);
        if (lane >= off) x += y;
    }
    if (lane == 63) wsum[wid] = x;
    __syncthreads();
    if (wid == 0) {
        int y = (lane < 16) ? wsum[lane] : 0;
#pragma unroll
        for (int off = 1; off < 16; off <<= 1) {
            int t = __shfl_up(y, off, 64);
            if (lane >= off) y += t;
        }
        if (lane < 16) wsum[lane] = y;
    }
    __syncthreads();
    int woff = wid ? wsum[wid - 1] : 0;
    return woff + x - v;
}

__global__ __launch_bounds__(1024) void scan1_kernel(
    const int* __restrict__ cnt_store, int* __restrict__ scanex,
    int* __restrict__ bsum, int total)
{
    int tid = threadIdx.x;
    int i = blockIdx.x * 1024 + tid;
    int v = (i < total) ? cnt_store[i] : 0;
    int excl = block_excl_scan(v, tid);
    if (i < total) scanex[i] = excl;
    if (tid == 1023) bsum[blockIdx.x] = excl + v;
}

__global__ __launch_bounds__(1024) void scan2_kernel(int* __restrict__ bsum, int nb)
{
    int tid = threadIdx.x;
    int v = (tid < nb) ? bsum[tid] : 0;
    int excl = block_excl_scan(v, tid);
    if (tid < nb) bsum[tid] = excl;
}

__global__ __launch_bounds__(256) void scan3_kernel(
    const int* __restrict__ scanex, const int* __restrict__ bsum,
    int* __restrict__ cursor_base, int* __restrict__ bucket_ptr,
    int total, int E)
{
    int i = blockIdx.x * 256 + threadIdx.x;
    if (i >= total) return;
    int v = scanex[i] + bsum[i >> 10];
    int rel = i / (NB * GF);
    int rem = i - rel * (NB * GF);
    int b = rem / GF, rep = rem - b * GF;
    int local = v - rel * E;            // each relation has exactly E edges
    cursor_base[i] = local;
    if (rep == 0) bucket_ptr[rel * (NB + 1) + b] = local;
    if (rem == 0) bucket_ptr[rel * (NB + 1) + NB] = E;
}

// ---- fill: coarse bucket sort of (src, dlocal, raw w); LDS cursors ---------
__global__ __launch_bounds__(512) void fill_kernel(
    const int* __restrict__ src, const int* __restrict__ dst,
    const float* __restrict__ w, const int* __restrict__ cursor_base_r,
    ull* __restrict__ csr8, int E)
{
    __shared__ int lcur[NB];
    const int rep = blockIdx.x;
    const int tid = threadIdx.x;
    for (int b = tid; b < NB; b += 512)
        lcur[b] = cursor_base_r[(size_t)b * GF + rep];
    __syncthreads();
    const int es  = (E + GF - 1) / GF;
    const int beg = rep * es;
    const int end = min(beg + es, E);
    for (int e = beg + tid; e < end; e += 512) {
        int s = src[e];
        int d = dst[e];
        int pos = atomicAdd(&lcur[d >> 6], 1);
        ull rec = (ull)(unsigned)(s | ((d & 63) << 16)) |
                  ((ull)__float_as_uint(w[e]) << 32);
        csr8[pos] = rec;
    }
}

// ---- sort2: bucket -> exact per-dst CSR (64 LDS bins) + row_ptr ------------
__global__ __launch_bounds__(256) void sort2_kernel(
    const int* __restrict__ bucket_ptr_r, const ull* __restrict__ csr8,
    ull* __restrict__ csr2, int* __restrict__ row_ptr_r, int E)
{
    __shared__ int cnt[64];
    __shared__ int cur[64];
    const int b = blockIdx.x;
    const int tid = threadIdx.x;
    const int beg = bucket_ptr_r[b];
    const int end = bucket_ptr_r[b + 1];
    if (tid < 64) cnt[tid] = 0;
    __syncthreads();
    for (int e = beg + tid; e < end; e += 256)
        atomicAdd(&cnt[(int)((csr8[e] >> 16) & 63)], 1);
    __syncthreads();
    if (tid < 64) {                      // wave 0: exclusive scan of 64 bins
        int v = cnt[tid];
        int x = v;
#pragma unroll
        for (int off = 1; off < 64; off <<= 1) {
            int y = __shfl_up(x, off, 64);
            if (tid >= off) x += y;
        }
        int start = beg + x - v;
        cur[tid] = start;
        row_ptr_r[b * 64 + tid] = start;
        if (b == 0 && tid == 0) row_ptr_r[NN] = E;
    }
    __syncthreads();
    for (int e = beg + tid; e < end; e += 256) {
        ull rec = csr8[e];
        int j = (int)((rec >> 16) & 63);
        int pos = atomicAdd(&cur[j], 1);
        csr2[pos] = rec;
    }
}

// ---- gather: one wave per dst node; 2 edges x 32 lanes x float4 ------------
// degin computed inline (row-sum of raw w); dego via rdego table
__global__ __launch_bounds__(256) void gather_kernel(
    const int* __restrict__ row_ptr_r, const ull* __restrict__ csr2,
    const float* __restrict__ rdego_r, const float* __restrict__ h,
    float* __restrict__ agg, int n)
{
    int node = (blockIdx.x * 256 + threadIdx.x) >> 6;
    int lane = threadIdx.x & 63;
    if (node >= n) return;
    int beg = row_ptr_r[node], end = row_ptr_r[node + 1];

    // pass 1: degin = row-sum of raw w
    float sw = 0.f;
    for (int e = beg + lane; e < end; e += 64)
        sw += __uint_as_float((unsigned)(csr2[e] >> 32));
#pragma unroll
    for (int off = 32; off; off >>= 1) sw += __shfl_xor(sw, off, 64);
    float rsw = rsqrtf(sw);

    // pass 2: two edges concurrently; 32 lanes x float4 each
    const int half = lane >> 5, l32 = lane & 31;
    float4 acc = make_float4(0.f, 0.f, 0.f, 0.f);
    int e = beg;
    for (; e + 2 <= end; e += 2) {
        ull rec = csr2[e + half];
        int s = (int)(rec & 0xFFFF);
        float wn = __uint_as_float((unsigned)(rec >> 32)) * rdego_r[s] * rsw;
        float4 hv = *(const float4*)(h + (size_t)s * D + l32 * 4);
        acc.x += wn * hv.x; acc.y += wn * hv.y;
        acc.z += wn * hv.z; acc.w += wn * hv.w;
    }
    if (e < end && half == 0) {          // odd tail
        ull rec = csr2[e];
        int s = (int)(rec & 0xFFFF);
        float wn = __uint_as_float((unsigned)(rec >> 32)) * rdego_r[s] * rsw;
        float4 hv = *(const float4*)(h + (size_t)s * D + l32 * 4);
        acc.x += wn * hv.x; acc.y += wn * hv.y;
        acc.z += wn * hv.z; acc.w += wn * hv.w;
    }
    acc.x += __shfl_xor(acc.x, 32, 64);
    acc.y += __shfl_xor(acc.y, 32, 64);
    acc.z += __shfl_xor(acc.z, 32, 64);
    acc.w += __shfl_xor(acc.w, 32, 64);
    if (half == 0)
        *(float4*)(agg + (size_t)node * D + l32 * 4) = acc;
}

// ---- proj: agg @ W, fused bias+ReLU+0.5*merge ------------------------------
__global__ __launch_bounds__(256) void proj_fused_kernel(
    const float* __restrict__ h, const float* __restrict__ W,
    const float* __restrict__ b, float* __restrict__ out, int add)
{
    __shared__ float Ws[64 * D];
    __shared__ float Hs[32 * D];
    const int t = threadIdx.x;
    const int row0 = blockIdx.x * 32;

    const float4* H4 = (const float4*)(h + (size_t)row0 * D);
    float4* Hs4 = (float4*)Hs;
#pragma unroll
    for (int i = 0; i < 4; ++i) Hs4[t + 256 * i] = H4[t + 256 * i];

    const int c0 = (t & 31) * 4;
    const int r0 = (t >> 5) * 4;
    float acc[4][4] = {};

    for (int kc = 0; kc < 2; ++kc) {
        __syncthreads();
        const float4* W4 = (const float4*)(W + (size_t)kc * 64 * D);
        float4* Ws4 = (float4*)Ws;
#pragma unroll
        for (int i = 0; i < 8; ++i) Ws4[t + 256 * i] = W4[t + 256 * i];
        __syncthreads();

        for (int k = 0; k < 64; ++k) {
            float4 wv = *(const float4*)&Ws[k * D + c0];
            float h0 = Hs[(r0 + 0) * D + kc * 64 + k];
            float h1 = Hs[(r0 + 1) * D + kc * 64 + k];
            float h2 = Hs[(r0 + 2) * D + kc * 64 + k];
            float h3 = Hs[(r0 + 3) * D + kc * 64 + k];
            acc[0][0] += h0 * wv.x; acc[0][1] += h0 * wv.y; acc[0][2] += h0 * wv.z; acc[0][3] += h0 * wv.w;
            acc[1][0] += h1 * wv.x; acc[1][1] += h1 * wv.y; acc[1][2] += h1 * wv.z; acc[1][3] += h1 * wv.w;
            acc[2][0] += h2 * wv.x; acc[2][1] += h2 * wv.y; acc[2][2] += h2 * wv.z; acc[2][3] += h2 * wv.w;
            acc[3][0] += h3 * wv.x; acc[3][1] += h3 * wv.y; acc[3][2] += h3 * wv.z; acc[3][3] += h3 * wv.w;
        }
    }

    float4 bv = *(const float4*)&b[c0];
#pragma unroll
    for (int r = 0; r < 4; ++r) {
        float* op = &out[(size_t)(row0 + r0 + r) * D + c0];
        float4 v;
        v.x = 0.5f * fmaxf(acc[r][0] + bv.x, 0.0f);
        v.y = 0.5f * fmaxf(acc[r][1] + bv.y, 0.0f);
        v.z = 0.5f * fmaxf(acc[r][2] + bv.z, 0.0f);
        v.w = 0.5f * fmaxf(acc[r][3] + bv.w, 0.0f);
        if (add) {
            float4 o = *(const float4*)op;
            v.x += o.x; v.y += o.y; v.z += o.z; v.w += o.w;
        }
        *(float4*)op = v;
    }
}

extern "C" void kernel_launch(void* const* d_in, const int* in_sizes, int n_in,
                              void* d_out, int out_size, void* d_ws, size_t ws_size,
                              hipStream_t stream) {
    const float* com_emb = (const float*)d_in[0];
    const float* pos_emb = (const float*)d_in[1];
    const int E = in_sizes[2];       // 1,000,000
    const int N = NN;

    float* out = (float*)d_out;
    float* out_com = out;
    float* out_pos = out + (size_t)N * D;

    // relation order: 0=cflow(com->com) 1=supply(pos->com) 2=pflow(pos->pos) 3=demand(com->pos)
    Ptrs ptrs;
    ptrs.src[0] = (const int*)d_in[8];  ptrs.dst[0] = (const int*)d_in[9];  ptrs.w[0] = (const float*)d_in[10];
    ptrs.src[1] = (const int*)d_in[5];  ptrs.dst[1] = (const int*)d_in[6];  ptrs.w[1] = (const float*)d_in[7];
    ptrs.src[2] = (const int*)d_in[11]; ptrs.dst[2] = (const int*)d_in[12]; ptrs.w[2] = (const float*)d_in[13];
    ptrs.src[3] = (const int*)d_in[2];  ptrs.dst[3] = (const int*)d_in[3];  ptrs.w[3] = (const float*)d_in[4];

    // ws layout (~41.6 MB); histo_rep overlaid with agg (dead after reduce)
    const int totalCnt = 4 * NB * GF;           // 320000
    char* p = (char*)d_ws;
    float* rdego       = (float*)p;  p += (size_t)4 * N * 4;              // 0.64 MB
    int*   cnt_store   = (int*)p;    p += (size_t)totalCnt * 4;           // 1.28 MB
    int*   scanex      = (int*)p;    p += (size_t)totalCnt * 4;           // 1.28 MB
    int*   bsum        = (int*)p;    p += (size_t)1024 * 4;
    int*   cursor_base = (int*)p;    p += (size_t)totalCnt * 4;           // 1.28 MB
    int*   bucket_ptr  = (int*)p;    p += (size_t)4 * (NB + 1) * 4;
    int*   row_ptr     = (int*)p;    p += (size_t)4 * (N + 1) * 4;        // 0.64 MB
    ull*   csr8        = (ull*)p;    p += (size_t)E * 8;                  // 8 MB
    ull*   csr2        = (ull*)p;    p += (size_t)E * 8;                  // 8 MB
    float* histo_rep   = (float*)p;                                       // 20.48 MB
    float* agg         = (float*)p;                                       // (overlay)

    hist_kernel<<<4 * 2 * GH, 1024, 0, stream>>>(ptrs, histo_rep, E);
    reduce_kernel<<<(4 * N + 255) / 256, 256, 0, stream>>>(histo_rep, rdego, 4 * N);
    bcnt_kernel<<<4 * GF, 256, 0, stream>>>(ptrs, cnt_store, E);
    const int sBlocks = (totalCnt + 1023) / 1024;
    scan1_kernel<<<sBlocks, 1024, 0, stream>>>(cnt_store, scanex, bsum, totalCnt);
    scan2_kernel<<<1, 1024, 0, stream>>>(bsum, sBlocks);
    scan3_kernel<<<(totalCnt + 255) / 256, 256, 0, stream>>>(scanex, bsum, cursor_base,
                                                             bucket_ptr, totalCnt, E);

    const int gBlocks = N / 4;                 // 1 wave per dst node
    const int pBlocks = N / 32;
    auto run_rel = [&](int rel, const float* h, const float* W, const float* b,
                       float* oh, int add) {
        int* rp = row_ptr + (size_t)rel * (N + 1);
        fill_kernel<<<GF, 512, 0, stream>>>(ptrs.src[rel], ptrs.dst[rel], ptrs.w[rel],
                                            cursor_base + (size_t)rel * NB * GF, csr8, E);
        sort2_kernel<<<NB, 256, 0, stream>>>(bucket_ptr + (size_t)rel * (NB + 1), csr8,
                                             csr2, rp, E);
        gather_kernel<<<gBlocks, 256, 0, stream>>>(rp, csr2, rdego + (size_t)rel * N,
                                                   h, agg, N);
        proj_fused_kernel<<<pBlocks, 256, 0, stream>>>(agg, W, b, oh, add);
    };

    run_rel(0, com_emb, (const float*)d_in[18], (const float*)d_in[19], out_com, 0); // cflow
    run_rel(1, pos_emb, (const float*)d_in[16], (const float*)d_in[17], out_com, 1); // supply
    run_rel(2, pos_emb, (const float*)d_in[20], (const float*)d_in[21], out_pos, 0); // pflow
    run_rel(3, com_emb, (const float*)d_in[14], (const float*)d_in[15], out_pos, 1); // demand
}

// Round 7
// 505.060 us; speedup vs baseline: 6.9478x; 1.0658x over previous
//
#include <hip/hip_runtime.h>
#include <hip/hip_fp16.h>

#define D   128
#define NN  40000
#define HH  10000    // histogram quarter-table size (40 KB LDS)
#define NB  625      // dst buckets per relation (64 nodes each)
#define GH  16       // histogram replica slices
#define GF  128      // fill slices (= fill grid per relation)

typedef unsigned long long ull;

struct Ptrs { const int* src[4]; const int* dst[4]; const float* w[4]; };

// ---- convert f32 table -> fp16 (8 elems/thread) ----------------------------
__global__ __launch_bounds__(256) void conv_kernel(
    const float* __restrict__ in, __half* __restrict__ out, int n8)
{
    int i = blockIdx.x * 256 + threadIdx.x;
    if (i >= n8) return;
    const float4* a = (const float4*)in + (size_t)i * 2;
    float4 v0 = a[0], v1 = a[1];
    __half2 pack[4];
    pack[0] = __floats2half2_rn(v0.x, v0.y);
    pack[1] = __floats2half2_rn(v0.z, v0.w);
    pack[2] = __floats2half2_rn(v1.x, v1.y);
    pack[3] = __floats2half2_rn(v1.z, v1.w);
    ((float4*)out)[i] = *(float4*)pack;
}

// ---- weighted out-degree: quarter-table LDS histograms ---------------------
// grid = 4 rel x 4 quarter x GH reps = 256 blocks x 512 thr; no global atomics
__global__ __launch_bounds__(512) void hist_kernel(
    Ptrs p, float* __restrict__ histo_rep, int E)
{
    __shared__ float hist[HH];          // 40 KB -> 4 blocks/CU (wave-capped ok)
    const int bx  = blockIdx.x;         // ((rel*4 + q)*GH + rep)
    const int rep = bx & (GH - 1);
    const int q   = (bx >> 4) & 3;
    const int rel = bx >> 6;
    const int tid = threadIdx.x;

    for (int i = tid; i < HH; i += 512) hist[i] = 0.f;
    __syncthreads();

    const int es  = (E + GH - 1) / GH;
    const int beg = rep * es;
    const int end = min(beg + es, E);
    const int* idx = p.src[rel];
    const float* w = p.w[rel];
    const int base = q * HH;
    for (int e = beg + tid; e < end; e += 512) {
        int v = idx[e] - base;
        if ((unsigned)v < HH) atomicAdd(&hist[v], w[e]);
    }
    __syncthreads();

    float* outp = histo_rep + (size_t)bx * HH;
    for (int i = tid; i < HH; i += 512) outp[i] = hist[i];
}

// ---- reduce replicas -> rdego[rel][node] = rsqrt(weighted out-degree) ------
__global__ __launch_bounds__(256) void reduce_kernel(
    const float* __restrict__ histo_rep, float* __restrict__ rdego, int total)
{
    int i = blockIdx.x * 256 + threadIdx.x;     // i = rel*NN + node
    if (i >= total) return;
    int rel = i / NN;
    int node = i - rel * NN;
    int q = node / HH;
    int hn = node - q * HH;
    const float* basep = histo_rep + ((size_t)((rel * 4 + q) * GH)) * HH + hn;
    float v = 0.f;
#pragma unroll
    for (int r = 0; r < GH; ++r) v += basep[(size_t)r * HH];
    rdego[i] = rsqrtf(v);
}

// ---- per-(rel,slice) coarse bucket counts in tiny LDS ----------------------
__global__ __launch_bounds__(256) void bcnt_kernel(
    Ptrs p, int* __restrict__ cnt_store, int E)
{
    __shared__ int cnt[NB];
    const int rel = blockIdx.x / GF;
    const int rep = blockIdx.x - rel * GF;
    const int tid = threadIdx.x;
    for (int b = tid; b < NB; b += 256) cnt[b] = 0;
    __syncthreads();
    const int es  = (E + GF - 1) / GF;
    const int beg = rep * es;
    const int end = min(beg + es, E);
    const int* dst = p.dst[rel];
    for (int e = beg + tid; e < end; e += 256)
        atomicAdd(&cnt[dst[e] >> 6], 1);
    __syncthreads();
    for (int b = tid; b < NB; b += 256)
        cnt_store[((size_t)(rel * NB + b)) * GF + rep] = cnt[b];
}

// ---- 3-kernel scan over 4*NB*GF = 320000 counts ----------------------------
__device__ inline int block_excl_scan(int v, int tid) {
    __shared__ int wsum[16];
    int lane = tid & 63, wid = tid >> 6;
    int x = v;
#pragma unroll
    for (int off = 1; off < 64; off <<= 1) {
        int y = __shfl_up(x, off, 64);
        if (lane >= off) x += y;
    }
    if (lane == 63) wsum[wid] = x;
    __syncthreads();
    if (wid == 0) {
        int y = (lane < 16) ? wsum[lane] : 0;
#pragma unroll
        for (int off = 1; off < 16; off <<= 1) {
            int t = __shfl_up(y, off, 64);
            if (lane >= off) y += t;
        }
        if (lane < 16) wsum[lane] = y;
    }
    __syncthreads();
    int woff = wid ? wsum[wid - 1] : 0;
    return woff + x - v;
}

__global__ __launch_bounds__(1024) void scan1_kernel(
    const int* __restrict__ cnt_store, int* __restrict__ scanex,
    int* __restrict__ bsum, int total)
{
    int tid = threadIdx.x;
    int i = blockIdx.x * 1024 + tid;
    int v = (i < total) ? cnt_store[i] : 0;
    int excl = block_excl_scan(v, tid);
    if (i < total) scanex[i] = excl;
    if (tid == 1023) bsum[blockIdx.x] = excl + v;
}

__global__ __launch_bounds__(1024) void scan2_kernel(int* __restrict__ bsum, int nb)
{
    int tid = threadIdx.x;
    int v = (tid < nb) ? bsum[tid] : 0;
    int excl = block_excl_scan(v, tid);
    if (tid < nb) bsum[tid] = excl;
}

__global__ __launch_bounds__(256) void scan3_kernel(
    const int* __restrict__ scanex, const int* __restrict__ bsum,
    int* __restrict__ cursor_base, int* __restrict__ bucket_ptr,
    int total, int E)
{
    int i = blockIdx.x * 256 + threadIdx.x;
    if (i >= total) return;
    int v = scanex[i] + bsum[i >> 10];
    int rel = i / (NB * GF);
    int rem = i - rel * (NB * GF);
    int b = rem / GF, rep = rem - b * GF;
    int local = v - rel * E;            // each relation has exactly E edges
    cursor_base[i] = local;
    if (rep == 0) bucket_ptr[rel * (NB + 1) + b] = local;
    if (rem == 0) bucket_ptr[rel * (NB + 1) + NB] = E;
}

// ---- fill: coarse bucket sort of (src, dlocal, raw w); LDS cursors ---------
__global__ __launch_bounds__(512) void fill_kernel(
    const int* __restrict__ src, const int* __restrict__ dst,
    const float* __restrict__ w, const int* __restrict__ cursor_base_r,
    ull* __restrict__ csr8, int E)
{
    __shared__ int lcur[NB];
    const int rep = blockIdx.x;
    const int tid = threadIdx.x;
    for (int b = tid; b < NB; b += 512)
        lcur[b] = cursor_base_r[(size_t)b * GF + rep];
    __syncthreads();
    const int es  = (E + GF - 1) / GF;
    const int beg = rep * es;
    const int end = min(beg + es, E);
    for (int e = beg + tid; e < end; e += 512) {
        int s = src[e];
        int d = dst[e];
        int pos = atomicAdd(&lcur[d >> 6], 1);
        ull rec = (ull)(unsigned)(s | ((d & 63) << 16)) |
                  ((ull)__float_as_uint(w[e]) << 32);
        csr8[pos] = rec;
    }
}

// ---- sort2: bucket -> exact per-dst CSR; bake wn = w*rdego[s]*rsqrt(degin) -
__global__ __launch_bounds__(256) void sort2_kernel(
    const int* __restrict__ bucket_ptr_r, const ull* __restrict__ csr8,
    const float* __restrict__ rdego_r, ull* __restrict__ csr2,
    int* __restrict__ row_ptr_r, int E)
{
    __shared__ int cnt[64];
    __shared__ int cur[64];
    __shared__ float swsum[64];
    const int b = blockIdx.x;
    const int tid = threadIdx.x;
    const int beg = bucket_ptr_r[b];
    const int end = bucket_ptr_r[b + 1];
    if (tid < 64) { cnt[tid] = 0; swsum[tid] = 0.f; }
    __syncthreads();
    for (int e = beg + tid; e < end; e += 256) {
        ull rec = csr8[e];
        int j = (int)((rec >> 16) & 63);
        atomicAdd(&cnt[j], 1);
        atomicAdd(&swsum[j], __uint_as_float((unsigned)(rec >> 32)));
    }
    __syncthreads();
    if (tid < 64) {                      // wave 0: exclusive scan of 64 bins
        int v = cnt[tid];
        int x = v;
#pragma unroll
        for (int off = 1; off < 64; off <<= 1) {
            int y = __shfl_up(x, off, 64);
            if (tid >= off) x += y;
        }
        int start = beg + x - v;
        cur[tid] = start;
        row_ptr_r[b * 64 + tid] = start;
        swsum[tid] = rsqrtf(swsum[tid]);
        if (b == 0 && tid == 0) row_ptr_r[NN] = E;
    }
    __syncthreads();
    for (int e = beg + tid; e < end; e += 256) {
        ull rec = csr8[e];
        int j = (int)((rec >> 16) & 63);
        int s = (int)(rec & 0xFFFF);
        float wn = __uint_as_float((unsigned)(rec >> 32)) * rdego_r[s] * swsum[j];
        int pos = atomicAdd(&cur[j], 1);
        csr2[pos] = (ull)(unsigned)s | ((ull)__float_as_uint(wn) << 32);
    }
}

// ---- gather: one wave per dst node; 4 edges x 16 lanes x 16B fp16 rows -----
__global__ __launch_bounds__(256) void gather16_kernel(
    const int* __restrict__ row_ptr_r, const ull* __restrict__ csr2,
    const __half* __restrict__ h16, __half* __restrict__ agg16, int n)
{
    int node = (blockIdx.x * 256 + threadIdx.x) >> 6;
    int lane = threadIdx.x & 63;
    if (node >= n) return;
    int beg = row_ptr_r[node], end = row_ptr_r[node + 1];
    const int g = lane >> 4, l16 = lane & 15;

    float acc[8] = {};
    for (int e = beg; e < end; e += 4) {
        int ee = e + g;
        int valid = ee < end;
        ull rec = csr2[valid ? ee : (end - 1)];
        int s = (int)(rec & 0xFFFF);
        float wn = valid ? __uint_as_float((unsigned)(rec >> 32)) : 0.f;
        float4 hv4 = ((const float4*)(h16 + (size_t)s * D))[l16];
        __half2* hp = (__half2*)&hv4;
        float2 f0 = __half22float2(hp[0]);
        float2 f1 = __half22float2(hp[1]);
        float2 f2 = __half22float2(hp[2]);
        float2 f3 = __half22float2(hp[3]);
        acc[0] += wn * f0.x; acc[1] += wn * f0.y;
        acc[2] += wn * f1.x; acc[3] += wn * f1.y;
        acc[4] += wn * f2.x; acc[5] += wn * f2.y;
        acc[6] += wn * f3.x; acc[7] += wn * f3.y;
    }
#pragma unroll
    for (int k = 0; k < 8; ++k) {
        acc[k] += __shfl_xor(acc[k], 16, 64);
        acc[k] += __shfl_xor(acc[k], 32, 64);
    }
    if (g == 0) {
        __half2 pack[4];
        pack[0] = __floats2half2_rn(acc[0], acc[1]);
        pack[1] = __floats2half2_rn(acc[2], acc[3]);
        pack[2] = __floats2half2_rn(acc[4], acc[5]);
        pack[3] = __floats2half2_rn(acc[6], acc[7]);
        ((float4*)(agg16 + (size_t)node * D))[l16] = *(float4*)pack;
    }
}

// ---- proj: agg16 @ W, fused bias+ReLU+0.5*merge ----------------------------
__global__ __launch_bounds__(256) void proj_fused_kernel(
    const __half* __restrict__ agg16, const float* __restrict__ W,
    const float* __restrict__ b, float* __restrict__ out, int add)
{
    __shared__ float Ws[64 * D];
    __shared__ float Hs[32 * D];
    const int t = threadIdx.x;
    const int row0 = blockIdx.x * 32;

    // stage 32x128 fp16 rows, convert to f32 in LDS
    const float4* A4 = (const float4*)(agg16 + (size_t)row0 * D);
    for (int i = t; i < 512; i += 256) {
        float4 v = A4[i];
        __half2* hp = (__half2*)&v;
        float2 f0 = __half22float2(hp[0]);
        float2 f1 = __half22float2(hp[1]);
        float2 f2 = __half22float2(hp[2]);
        float2 f3 = __half22float2(hp[3]);
        *(float4*)&Hs[i * 8]     = make_float4(f0.x, f0.y, f1.x, f1.y);
        *(float4*)&Hs[i * 8 + 4] = make_float4(f2.x, f2.y, f3.x, f3.y);
    }

    const int c0 = (t & 31) * 4;
    const int r0 = (t >> 5) * 4;
    float acc[4][4] = {};

    for (int kc = 0; kc < 2; ++kc) {
        __syncthreads();
        const float4* W4 = (const float4*)(W + (size_t)kc * 64 * D);
        float4* Ws4 = (float4*)Ws;
#pragma unroll
        for (int i = 0; i < 8; ++i) Ws4[t + 256 * i] = W4[t + 256 * i];
        __syncthreads();

        for (int k = 0; k < 64; ++k) {
            float4 wv = *(const float4*)&Ws[k * D + c0];
            float h0 = Hs[(r0 + 0) * D + kc * 64 + k];
            float h1 = Hs[(r0 + 1) * D + kc * 64 + k];
            float h2 = Hs[(r0 + 2) * D + kc * 64 + k];
            float h3 = Hs[(r0 + 3) * D + kc * 64 + k];
            acc[0][0] += h0 * wv.x; acc[0][1] += h0 * wv.y; acc[0][2] += h0 * wv.z; acc[0][3] += h0 * wv.w;
            acc[1][0] += h1 * wv.x; acc[1][1] += h1 * wv.y; acc[1][2] += h1 * wv.z; acc[1][3] += h1 * wv.w;
            acc[2][0] += h2 * wv.x; acc[2][1] += h2 * wv.y; acc[2][2] += h2 * wv.z; acc[2][3] += h2 * wv.w;
            acc[3][0] += h3 * wv.x; acc[3][1] += h3 * wv.y; acc[3][2] += h3 * wv.z; acc[3][3] += h3 * wv.w;
        }
    }

    float4 bv = *(const float4*)&b[c0];
#pragma unroll
    for (int r = 0; r < 4; ++r) {
        float* op = &out[(size_t)(row0 + r0 + r) * D + c0];
        float4 v;
        v.x = 0.5f * fmaxf(acc[r][0] + bv.x, 0.0f);
        v.y = 0.5f * fmaxf(acc[r][1] + bv.y, 0.0f);
        v.z = 0.5f * fmaxf(acc[r][2] + bv.z, 0.0f);
        v.w = 0.5f * fmaxf(acc[r][3] + bv.w, 0.0f);
        if (add) {
            float4 o = *(const float4*)op;
            v.x += o.x; v.y += o.y; v.z += o.z; v.w += o.w;
        }
        *(float4*)op = v;
    }
}

extern "C" void kernel_launch(void* const* d_in, const int* in_sizes, int n_in,
                              void* d_out, int out_size, void* d_ws, size_t ws_size,
                              hipStream_t stream) {
    const float* com_emb = (const float*)d_in[0];
    const float* pos_emb = (const float*)d_in[1];
    const int E = in_sizes[2];       // 1,000,000
    const int N = NN;

    float* out = (float*)d_out;
    float* out_com = out;
    float* out_pos = out + (size_t)N * D;

    // relation order: 0=cflow(com->com) 1=supply(pos->com) 2=pflow(pos->pos) 3=demand(com->pos)
    Ptrs ptrs;
    ptrs.src[0] = (const int*)d_in[8];  ptrs.dst[0] = (const int*)d_in[9];  ptrs.w[0] = (const float*)d_in[10];
    ptrs.src[1] = (const int*)d_in[5];  ptrs.dst[1] = (const int*)d_in[6];  ptrs.w[1] = (const float*)d_in[7];
    ptrs.src[2] = (const int*)d_in[11]; ptrs.dst[2] = (const int*)d_in[12]; ptrs.w[2] = (const float*)d_in[13];
    ptrs.src[3] = (const int*)d_in[2];  ptrs.dst[3] = (const int*)d_in[3];  ptrs.w[3] = (const float*)d_in[4];

    // ws layout (~41.6 MB); histo_rep (dead after reduce) overlaid with agg16
    const int totalCnt = 4 * NB * GF;           // 320000
    char* p = (char*)d_ws;
    float* rdego       = (float*)p;  p += (size_t)4 * N * 4;              // 0.64 MB
    int*   cnt_store   = (int*)p;    p += (size_t)totalCnt * 4;           // 1.28 MB
    int*   scanex      = (int*)p;    p += (size_t)totalCnt * 4;           // 1.28 MB
    int*   bsum        = (int*)p;    p += (size_t)1024 * 4;
    int*   cursor_base = (int*)p;    p += (size_t)totalCnt * 4;           // 1.28 MB
    int*   bucket_ptr  = (int*)p;    p += (size_t)4 * (NB + 1) * 4;
    int*   row_ptr     = (int*)p;    p += (size_t)4 * (N + 1) * 4;        // 0.64 MB
    ull*   csr8        = (ull*)p;    p += (size_t)E * 8;                  // 8 MB
    ull*   csr2        = (ull*)p;    p += (size_t)E * 8;                  // 8 MB
    __half* h16        = (__half*)p; p += (size_t)N * D * 2;              // 10.24 MB
    float* histo_rep   = (float*)p;                                       // 10.24 MB
    __half* agg16      = (__half*)p;                                      // (overlay)

    hist_kernel<<<256, 512, 0, stream>>>(ptrs, histo_rep, E);
    reduce_kernel<<<(4 * N + 255) / 256, 256, 0, stream>>>(histo_rep, rdego, 4 * N);
    bcnt_kernel<<<4 * GF, 256, 0, stream>>>(ptrs, cnt_store, E);
    const int sBlocks = (totalCnt + 1023) / 1024;
    scan1_kernel<<<sBlocks, 1024, 0, stream>>>(cnt_store, scanex, bsum, totalCnt);
    scan2_kernel<<<1, 1024, 0, stream>>>(bsum, sBlocks);
    scan3_kernel<<<(totalCnt + 255) / 256, 256, 0, stream>>>(scanex, bsum, cursor_base,
                                                             bucket_ptr, totalCnt, E);

    const int cBlocks = (N * D / 8 + 255) / 256;
    const int gBlocks = N / 4;                 // 1 wave per dst node
    const int pBlocks = N / 32;
    auto run_rel = [&](int rel, const float* W, const float* b,
                       float* oh, int add) {
        int* rp = row_ptr + (size_t)rel * (N + 1);
        fill_kernel<<<GF, 512, 0, stream>>>(ptrs.src[rel], ptrs.dst[rel], ptrs.w[rel],
                                            cursor_base + (size_t)rel * NB * GF, csr8, E);
        sort2_kernel<<<NB, 256, 0, stream>>>(bucket_ptr + (size_t)rel * (NB + 1), csr8,
                                             rdego + (size_t)rel * N, csr2, rp, E);
        gather16_kernel<<<gBlocks, 256, 0, stream>>>(rp, csr2, h16, agg16, N);
        proj_fused_kernel<<<pBlocks, 256, 0, stream>>>(agg16, W, b, oh, add);
    };

    conv_kernel<<<cBlocks, 256, 0, stream>>>(com_emb, h16, N * D / 8);
    run_rel(0, (const float*)d_in[18], (const float*)d_in[19], out_com, 0); // cflow (com)
    conv_kernel<<<cBlocks, 256, 0, stream>>>(pos_emb, h16, N * D / 8);
    run_rel(1, (const float*)d_in[16], (const float*)d_in[17], out_com, 1); // supply (pos)
    run_rel(2, (const float*)d_in[20], (const float*)d_in[21], out_pos, 0); // pflow (pos)
    conv_kernel<<<cBlocks, 256, 0, stream>>>(com_emb, h16, N * D / 8);
    run_rel(3, (const float*)d_in[14], (const float*)d_in[15], out_pos, 1); // demand (com)
}

// Round 8
// 459.948 us; speedup vs baseline: 7.6292x; 1.0981x over previous
//
#include <hip/hip_runtime.h>
#include <hip/hip_fp16.h>

#define D   128
#define NN  40000
#define NB  625      // dst buckets per relation (64 nodes each)
#define GH  64       // histogram slices per relation (partition, no overlap)
#define GF  128      // fill slices (= fill grid per relation)

typedef unsigned long long ull;

struct Ptrs { const int* src[4]; const int* dst[4]; const float* w[4]; };

// ---- convert f32 table -> fp16 (8 elems/thread) ----------------------------
__global__ __launch_bounds__(256) void conv_kernel(
    const float* __restrict__ in, __half* __restrict__ out, int n8)
{
    int i = blockIdx.x * 256 + threadIdx.x;
    if (i >= n8) return;
    const float4* a = (const float4*)in + (size_t)i * 2;
    float4 v0 = a[0], v1 = a[1];
    __half2 pack[4];
    pack[0] = __floats2half2_rn(v0.x, v0.y);
    pack[1] = __floats2half2_rn(v0.z, v0.w);
    pack[2] = __floats2half2_rn(v1.x, v1.y);
    pack[3] = __floats2half2_rn(v1.z, v1.w);
    ((float4*)out)[i] = *(float4*)pack;
}

// ---- weighted out-degree: FULL-table LDS histogram (156.25 KB) -------------
// grid = 4 rel x GH slices = 256 blocks x 1024 thr; each edge scanned once/rel
__global__ __launch_bounds__(1024) void hist_kernel(
    Ptrs p, __half* __restrict__ histo16, int E)
{
    __shared__ float hist[NN];          // 156.25 KB -> 1 block/CU, 16 waves
    const int bx  = blockIdx.x;         // rel*GH + rep
    const int rel = bx >> 6;
    const int rep = bx & (GH - 1);
    const int tid = threadIdx.x;

    for (int i = tid; i < NN; i += 1024) hist[i] = 0.f;
    __syncthreads();

    const int es  = (E + GH - 1) / GH;
    const int beg = rep * es;
    const int end = min(beg + es, E);
    const int* idx = p.src[rel];
    const float* w = p.w[rel];
    for (int e = beg + tid; e < end; e += 1024)
        atomicAdd(&hist[idx[e]], w[e]);
    __syncthreads();

    __half2* outp = (__half2*)(histo16 + (size_t)bx * NN);
    for (int i = tid; i < NN / 2; i += 1024)
        outp[i] = __floats2half2_rn(hist[2 * i], hist[2 * i + 1]);
}

// ---- reduce fp16 replicas -> rdego[rel][node] = rsqrt(out-degree) ----------
__global__ __launch_bounds__(256) void reduce_kernel(
    const __half* __restrict__ histo16, float* __restrict__ rdego, int total)
{
    int i = blockIdx.x * 256 + threadIdx.x;     // i = rel*NN + node
    if (i >= total) return;
    int rel = i / NN;
    int node = i - rel * NN;
    const __half* bp = histo16 + (size_t)rel * GH * NN + node;
    float v = 0.f;
#pragma unroll
    for (int r = 0; r < GH; ++r) v += __half2float(bp[(size_t)r * NN]);
    rdego[i] = rsqrtf(v);
}

// ---- per-(rel,slice) coarse bucket counts in tiny LDS ----------------------
__global__ __launch_bounds__(256) void bcnt_kernel(
    Ptrs p, int* __restrict__ cnt_store, int E)
{
    __shared__ int cnt[NB];
    const int rel = blockIdx.x / GF;
    const int rep = blockIdx.x - rel * GF;
    const int tid = threadIdx.x;
    for (int b = tid; b < NB; b += 256) cnt[b] = 0;
    __syncthreads();
    const int es  = (E + GF - 1) / GF;
    const int beg = rep * es;
    const int end = min(beg + es, E);
    const int* dst = p.dst[rel];
    for (int e = beg + tid; e < end; e += 256)
        atomicAdd(&cnt[dst[e] >> 6], 1);
    __syncthreads();
    for (int b = tid; b < NB; b += 256)
        cnt_store[((size_t)(rel * NB + b)) * GF + rep] = cnt[b];
}

// ---- 3-kernel scan over 4*NB*GF = 320000 counts ----------------------------
__device__ inline int block_excl_scan(int v, int tid) {
    __shared__ int wsum[16];
    int lane = tid & 63, wid = tid >> 6;
    int x = v;
#pragma unroll
    for (int off = 1; off < 64; off <<= 1) {
        int y = __shfl_up(x, off, 64);
        if (lane >= off) x += y;
    }
    if (lane == 63) wsum[wid] = x;
    __syncthreads();
    if (wid == 0) {
        int y = (lane < 16) ? wsum[lane] : 0;
#pragma unroll
        for (int off = 1; off < 16; off <<= 1) {
            int t = __shfl_up(y, off, 64);
            if (lane >= off) y += t;
        }
        if (lane < 16) wsum[lane] = y;
    }
    __syncthreads();
    int woff = wid ? wsum[wid - 1] : 0;
    return woff + x - v;
}

__global__ __launch_bounds__(1024) void scan1_kernel(
    const int* __restrict__ cnt_store, int* __restrict__ scanex,
    int* __restrict__ bsum, int total)
{
    int tid = threadIdx.x;
    int i = blockIdx.x * 1024 + tid;
    int v = (i < total) ? cnt_store[i] : 0;
    int excl = block_excl_scan(v, tid);
    if (i < total) scanex[i] = excl;
    if (tid == 1023) bsum[blockIdx.x] = excl + v;
}

__global__ __launch_bounds__(1024) void scan2_kernel(int* __restrict__ bsum, int nb)
{
    int tid = threadIdx.x;
    int v = (tid < nb) ? bsum[tid] : 0;
    int excl = block_excl_scan(v, tid);
    if (tid < nb) bsum[tid] = excl;
}

__global__ __launch_bounds__(256) void scan3_kernel(
    const int* __restrict__ scanex, const int* __restrict__ bsum,
    int* __restrict__ cursor_base, int* __restrict__ bucket_ptr,
    int total, int E)
{
    int i = blockIdx.x * 256 + threadIdx.x;
    if (i >= total) return;
    int v = scanex[i] + bsum[i >> 10];
    int rel = i / (NB * GF);
    int rem = i - rel * (NB * GF);
    int b = rem / GF, rep = rem - b * GF;
    int local = v - rel * E;            // each relation has exactly E edges
    cursor_base[i] = local;
    if (rep == 0) bucket_ptr[rel * (NB + 1) + b] = local;
    if (rem == 0) bucket_ptr[rel * (NB + 1) + NB] = E;
}

// ---- fill: coarse bucket sort of (src, dlocal, raw w); LDS cursors ---------
__global__ __launch_bounds__(512) void fill_kernel(
    const int* __restrict__ src, const int* __restrict__ dst,
    const float* __restrict__ w, const int* __restrict__ cursor_base_r,
    ull* __restrict__ csr8, int E)
{
    __shared__ int lcur[NB];
    const int rep = blockIdx.x;
    const int tid = threadIdx.x;
    for (int b = tid; b < NB; b += 512)
        lcur[b] = cursor_base_r[(size_t)b * GF + rep];
    __syncthreads();
    const int es  = (E + GF - 1) / GF;
    const int beg = rep * es;
    const int end = min(beg + es, E);
    for (int e = beg + tid; e < end; e += 512) {
        int s = src[e];
        int d = dst[e];
        int pos = atomicAdd(&lcur[d >> 6], 1);
        ull rec = (ull)(unsigned)(s | ((d & 63) << 16)) |
                  ((ull)__float_as_uint(w[e]) << 32);
        csr8[pos] = rec;
    }
}

// ---- sort2: bucket -> exact per-dst CSR; bake wn; 4B records ---------------
__global__ __launch_bounds__(256) void sort2_kernel(
    const int* __restrict__ bucket_ptr_r, const ull* __restrict__ csr8,
    const float* __restrict__ rdego_r, unsigned* __restrict__ csr2u,
    int* __restrict__ row_ptr_r, int E)
{
    __shared__ int cnt[64];
    __shared__ int cur[64];
    __shared__ float swsum[64];
    const int b = blockIdx.x;
    const int tid = threadIdx.x;
    const int beg = bucket_ptr_r[b];
    const int end = bucket_ptr_r[b + 1];
    if (tid < 64) { cnt[tid] = 0; swsum[tid] = 0.f; }
    __syncthreads();
    for (int e = beg + tid; e < end; e += 256) {
        ull rec = csr8[e];
        int j = (int)((rec >> 16) & 63);
        atomicAdd(&cnt[j], 1);
        atomicAdd(&swsum[j], __uint_as_float((unsigned)(rec >> 32)));
    }
    __syncthreads();
    if (tid < 64) {                      // wave 0: exclusive scan of 64 bins
        int v = cnt[tid];
        int x = v;
#pragma unroll
        for (int off = 1; off < 64; off <<= 1) {
            int y = __shfl_up(x, off, 64);
            if (tid >= off) x += y;
        }
        int start = beg + x - v;
        cur[tid] = start;
        row_ptr_r[b * 64 + tid] = start;
        swsum[tid] = rsqrtf(swsum[tid]);
        if (b == 0 && tid == 0) row_ptr_r[NN] = E;
    }
    __syncthreads();
    for (int e = beg + tid; e < end; e += 256) {
        ull rec = csr8[e];
        int j = (int)((rec >> 16) & 63);
        int s = (int)(rec & 0xFFFF);
        float wn = __uint_as_float((unsigned)(rec >> 32)) * rdego_r[s] * swsum[j];
        int pos = atomicAdd(&cur[j], 1);
        csr2u[pos] = (unsigned)s |
                     ((unsigned)__half_as_ushort(__float2half_rn(wn)) << 16);
    }
}

// ---- gather: one wave per dst node; 4 edges x 16 lanes x 16B fp16 rows -----
__global__ __launch_bounds__(256) void gather16_kernel(
    const int* __restrict__ row_ptr_r, const unsigned* __restrict__ csr2u,
    const __half* __restrict__ h16, __half* __restrict__ agg16, int n)
{
    int node = (blockIdx.x * 256 + threadIdx.x) >> 6;
    int lane = threadIdx.x & 63;
    if (node >= n) return;
    int beg = row_ptr_r[node], end = row_ptr_r[node + 1];
    const int g = lane >> 4, l16 = lane & 15;

    float acc[8] = {};
    for (int e = beg; e < end; e += 4) {
        int ee = e + g;
        int valid = ee < end;
        unsigned rec = csr2u[valid ? ee : (end - 1)];
        int s = (int)(rec & 0xFFFF);
        float wn = valid ? __half2float(__ushort_as_half((unsigned short)(rec >> 16))) : 0.f;
        float4 hv4 = ((const float4*)(h16 + (size_t)s * D))[l16];
        __half2* hp = (__half2*)&hv4;
        float2 f0 = __half22float2(hp[0]);
        float2 f1 = __half22float2(hp[1]);
        float2 f2 = __half22float2(hp[2]);
        float2 f3 = __half22float2(hp[3]);
        acc[0] += wn * f0.x; acc[1] += wn * f0.y;
        acc[2] += wn * f1.x; acc[3] += wn * f1.y;
        acc[4] += wn * f2.x; acc[5] += wn * f2.y;
        acc[6] += wn * f3.x; acc[7] += wn * f3.y;
    }
#pragma unroll
    for (int k = 0; k < 8; ++k) {
        acc[k] += __shfl_xor(acc[k], 16, 64);
        acc[k] += __shfl_xor(acc[k], 32, 64);
    }
    if (g == 0) {
        __half2 pack[4];
        pack[0] = __floats2half2_rn(acc[0], acc[1]);
        pack[1] = __floats2half2_rn(acc[2], acc[3]);
        pack[2] = __floats2half2_rn(acc[4], acc[5]);
        pack[3] = __floats2half2_rn(acc[6], acc[7]);
        ((float4*)(agg16 + (size_t)node * D))[l16] = *(float4*)pack;
    }
}

// ---- proj: agg16 @ W, fused bias+ReLU+0.5*merge ----------------------------
__global__ __launch_bounds__(256) void proj_fused_kernel(
    const __half* __restrict__ agg16, const float* __restrict__ W,
    const float* __restrict__ b, float* __restrict__ out, int add)
{
    __shared__ float Ws[64 * D];
    __shared__ float Hs[32 * D];
    const int t = threadIdx.x;
    const int row0 = blockIdx.x * 32;

    // stage 32x128 fp16 rows, convert to f32 in LDS
    const float4* A4 = (const float4*)(agg16 + (size_t)row0 * D);
    for (int i = t; i < 512; i += 256) {
        float4 v = A4[i];
        __half2* hp = (__half2*)&v;
        float2 f0 = __half22float2(hp[0]);
        float2 f1 = __half22float2(hp[1]);
        float2 f2 = __half22float2(hp[2]);
        float2 f3 = __half22float2(hp[3]);
        *(float4*)&Hs[i * 8]     = make_float4(f0.x, f0.y, f1.x, f1.y);
        *(float4*)&Hs[i * 8 + 4] = make_float4(f2.x, f2.y, f3.x, f3.y);
    }

    const int c0 = (t & 31) * 4;
    const int r0 = (t >> 5) * 4;
    float acc[4][4] = {};

    for (int kc = 0; kc < 2; ++kc) {
        __syncthreads();
        const float4* W4 = (const float4*)(W + (size_t)kc * 64 * D);
        float4* Ws4 = (float4*)Ws;
#pragma unroll
        for (int i = 0; i < 8; ++i) Ws4[t + 256 * i] = W4[t + 256 * i];
        __syncthreads();

        for (int k = 0; k < 64; ++k) {
            float4 wv = *(const float4*)&Ws[k * D + c0];
            float h0 = Hs[(r0 + 0) * D + kc * 64 + k];
            float h1 = Hs[(r0 + 1) * D + kc * 64 + k];
            float h2 = Hs[(r0 + 2) * D + kc * 64 + k];
            float h3 = Hs[(r0 + 3) * D + kc * 64 + k];
            acc[0][0] += h0 * wv.x; acc[0][1] += h0 * wv.y; acc[0][2] += h0 * wv.z; acc[0][3] += h0 * wv.w;
            acc[1][0] += h1 * wv.x; acc[1][1] += h1 * wv.y; acc[1][2] += h1 * wv.z; acc[1][3] += h1 * wv.w;
            acc[2][0] += h2 * wv.x; acc[2][1] += h2 * wv.y; acc[2][2] += h2 * wv.z; acc[2][3] += h2 * wv.w;
            acc[3][0] += h3 * wv.x; acc[3][1] += h3 * wv.y; acc[3][2] += h3 * wv.z; acc[3][3] += h3 * wv.w;
        }
    }

    float4 bv = *(const float4*)&b[c0];
#pragma unroll
    for (int r = 0; r < 4; ++r) {
        float* op = &out[(size_t)(row0 + r0 + r) * D + c0];
        float4 v;
        v.x = 0.5f * fmaxf(acc[r][0] + bv.x, 0.0f);
        v.y = 0.5f * fmaxf(acc[r][1] + bv.y, 0.0f);
        v.z = 0.5f * fmaxf(acc[r][2] + bv.z, 0.0f);
        v.w = 0.5f * fmaxf(acc[r][3] + bv.w, 0.0f);
        if (add) {
            float4 o = *(const float4*)op;
            v.x += o.x; v.y += o.y; v.z += o.z; v.w += o.w;
        }
        *(float4*)op = v;
    }
}

extern "C" void kernel_launch(void* const* d_in, const int* in_sizes, int n_in,
                              void* d_out, int out_size, void* d_ws, size_t ws_size,
                              hipStream_t stream) {
    const float* com_emb = (const float*)d_in[0];
    const float* pos_emb = (const float*)d_in[1];
    const int E = in_sizes[2];       // 1,000,000
    const int N = NN;

    float* out = (float*)d_out;
    float* out_com = out;
    float* out_pos = out + (size_t)N * D;

    // relation order: 0=cflow(com->com) 1=supply(pos->com) 2=pflow(pos->pos) 3=demand(com->pos)
    Ptrs ptrs;
    ptrs.src[0] = (const int*)d_in[8];  ptrs.dst[0] = (const int*)d_in[9];  ptrs.w[0] = (const float*)d_in[10];
    ptrs.src[1] = (const int*)d_in[5];  ptrs.dst[1] = (const int*)d_in[6];  ptrs.w[1] = (const float*)d_in[7];
    ptrs.src[2] = (const int*)d_in[11]; ptrs.dst[2] = (const int*)d_in[12]; ptrs.w[2] = (const float*)d_in[13];
    ptrs.src[3] = (const int*)d_in[2];  ptrs.dst[3] = (const int*)d_in[3];  ptrs.w[3] = (const float*)d_in[4];

    // ws layout (~38 MB). histo16 (20.48 MB, dead after reduce) overlays
    // csr8+csr2u+h16 (22.24 MB) — all written only after reduce completes.
    const int totalCnt = 4 * NB * GF;           // 320000
    char* p = (char*)d_ws;
    float* rdego       = (float*)p;  p += (size_t)4 * N * 4;              // 0.64 MB
    int*   cnt_store   = (int*)p;    p += (size_t)totalCnt * 4;           // 1.28 MB
    int*   scanex      = (int*)p;    p += (size_t)totalCnt * 4;           // 1.28 MB
    int*   bsum        = (int*)p;    p += (size_t)1024 * 4;
    int*   cursor_base = (int*)p;    p += (size_t)totalCnt * 4;           // 1.28 MB
    int*   bucket_ptr  = (int*)p;    p += (size_t)4 * (NB + 1) * 4;
    int*   row_ptr     = (int*)p;    p += (size_t)4 * (N + 1) * 4;        // 0.64 MB
    ull*   csr8        = (ull*)p;    p += (size_t)E * 8;                  // 8 MB
    unsigned* csr2u    = (unsigned*)p; p += (size_t)E * 4;                // 4 MB
    __half* h16        = (__half*)p; p += (size_t)N * D * 2;              // 10.24 MB
    __half* agg16      = (__half*)p;                                      // 10.24 MB
    __half* histo16    = (__half*)csr8;                                   // overlay

    hist_kernel<<<4 * GH, 1024, 0, stream>>>(ptrs, histo16, E);
    reduce_kernel<<<(4 * N + 255) / 256, 256, 0, stream>>>(histo16, rdego, 4 * N);
    bcnt_kernel<<<4 * GF, 256, 0, stream>>>(ptrs, cnt_store, E);
    const int sBlocks = (totalCnt + 1023) / 1024;
    scan1_kernel<<<sBlocks, 1024, 0, stream>>>(cnt_store, scanex, bsum, totalCnt);
    scan2_kernel<<<1, 1024, 0, stream>>>(bsum, sBlocks);
    scan3_kernel<<<(totalCnt + 255) / 256, 256, 0, stream>>>(scanex, bsum, cursor_base,
                                                             bucket_ptr, totalCnt, E);

    const int cBlocks = (N * D / 8 + 255) / 256;
    const int gBlocks = N / 4;                 // 1 wave per dst node
    const int pBlocks = N / 32;
    auto run_rel = [&](int rel, const float* W, const float* b,
                       float* oh, int add) {
        int* rp = row_ptr + (size_t)rel * (N + 1);
        fill_kernel<<<GF, 512, 0, stream>>>(ptrs.src[rel], ptrs.dst[rel], ptrs.w[rel],
                                            cursor_base + (size_t)rel * NB * GF, csr8, E);
        sort2_kernel<<<NB, 256, 0, stream>>>(bucket_ptr + (size_t)rel * (NB + 1), csr8,
                                             rdego + (size_t)rel * N, csr2u, rp, E);
        gather16_kernel<<<gBlocks, 256, 0, stream>>>(rp, csr2u, h16, agg16, N);
        proj_fused_kernel<<<pBlocks, 256, 0, stream>>>(agg16, W, b, oh, add);
    };

    conv_kernel<<<cBlocks, 256, 0, stream>>>(com_emb, h16, N * D / 8);
    run_rel(0, (const float*)d_in[18], (const float*)d_in[19], out_com, 0); // cflow (com)
    conv_kernel<<<cBlocks, 256, 0, stream>>>(pos_emb, h16, N * D / 8);
    run_rel(1, (const float*)d_in[16], (const float*)d_in[17], out_com, 1); // supply (pos)
    run_rel(2, (const float*)d_in[20], (const float*)d_in[21], out_pos, 0); // pflow (pos)
    conv_kernel<<<cBlocks, 256, 0, stream>>>(com_emb, h16, N * D / 8);
    run_rel(3, (const float*)d_in[14], (const float*)d_in[15], out_pos, 1); // demand (com)
}